// Round 11
// baseline (132.356 us; speedup 1.0000x reference)
//
#include <hip/hip_runtime.h>

typedef unsigned short u16;
typedef u16 u16x8 __attribute__((ext_vector_type(8)));
typedef __bf16 bf16x8 __attribute__((ext_vector_type(8)));
typedef float f32x4 __attribute__((ext_vector_type(4)));

#define EMB 1024
#define TT 2048
#define BB 2
#define NHEADS 16
#define HD 64
#define MTOT (BB * TT)  // 4096

// ---------- helpers ----------
__device__ __forceinline__ u16 cvt(float f) {  // native f32->bf16 (RTNE)
  return __builtin_bit_cast(u16, (__bf16)f);
}

__device__ __forceinline__ bf16x8 asbf(u16x8 v) {
  return __builtin_bit_cast(bf16x8, v);
}

__device__ __forceinline__ void gload16(const void* g, void* l) {
  __builtin_amdgcn_global_load_lds(
      (const __attribute__((address_space(1))) void*)g,
      (__attribute__((address_space(3))) void*)l, 16, 0, 0);
}

// ---------- fused prep: x->bf16 + 4x W transpose->bf16, one launch ----------
__global__ __launch_bounds__(256) void k_prep(
    const float* __restrict__ x, u16* __restrict__ xb,
    const float* __restrict__ W0, const float* __restrict__ W1,
    const float* __restrict__ W2, const float* __restrict__ W3,
    u16* __restrict__ T0, u16* __restrict__ T1, u16* __restrict__ T2,
    u16* __restrict__ T3) {
  __shared__ float tile[32][33];
  const int bid = blockIdx.x;
  const int tid = threadIdx.x;
  if (bid >= 4096) {  // x conversion: 2048 blocks x 2048 elems
    int i = (bid - 4096) * 256 + tid;
    float4 a = ((const float4*)x)[i * 2];
    float4 b = ((const float4*)x)[i * 2 + 1];
    u16x8 o;
    o[0] = cvt(a.x); o[1] = cvt(a.y); o[2] = cvt(a.z); o[3] = cvt(a.w);
    o[4] = cvt(b.x); o[5] = cvt(b.y); o[6] = cvt(b.z); o[7] = cvt(b.w);
    ((u16x8*)xb)[i] = o;
    return;
  }
  const int z = bid >> 10;  // which W
  const float* __restrict__ W = (z == 0) ? W0 : (z == 1) ? W1 : (z == 2) ? W2 : W3;
  u16* __restrict__ Wt = (z == 0) ? T0 : (z == 1) ? T1 : (z == 2) ? T2 : T3;
  const int b = bid & 1023;
  const int bx = (b & 31) * 32, by = (b >> 5) * 32;
  const int tx = tid & 31;
  const int ty = tid >> 5;  // 0..7
#pragma unroll
  for (int r = ty; r < 32; r += 8) tile[r][tx] = W[(by + r) * EMB + bx + tx];
  __syncthreads();
  // vectorized transposed store: each thread packs 2 cols into one dword
  const int tx2 = tid & 15;
  const int ty2 = tid >> 4;  // 0..15
#pragma unroll
  for (int r = ty2; r < 32; r += 16) {
    unsigned v = (unsigned)cvt(tile[2 * tx2][r]) |
                 ((unsigned)cvt(tile[2 * tx2 + 1][r]) << 16);
    *(unsigned*)&Wt[(bx + r) * EMB + by + 2 * tx2] = v;
  }
}

// ---------- fused QKV GEMM (BK=64, swizzled staging, packed epilogue) -----
// Q/K segments compute mfma(B,A): lane holds 4 CONSECUTIVE n (=d) at fixed
// m -> one uint2 (4x bf16) store. V keeps mfma(A,B): lane holds 4
// consecutive m (=t) at fixed d -> one uint2 store into Vt rows.
__global__ __launch_bounds__(256) void k_gemm_qkv(
    const u16* __restrict__ xb, const u16* __restrict__ WqT,
    const u16* __restrict__ WkT, const u16* __restrict__ WvT,
    const float* __restrict__ bq, const float* __restrict__ bk,
    const float* __restrict__ bv, u16* __restrict__ Q, u16* __restrict__ K,
    u16* __restrict__ Vt) {
  __shared__ u16 Al[128 * 64];  // 16 KB, 128B rows, XOR-swizzled chunks
  __shared__ u16 Bl[128 * 64];
  const int tid = threadIdx.x;
  const int lane = tid & 63;
  const int w = tid >> 6;
  const int wr = w >> 1, wc = w & 1;
  const int lr = lane & 15, lg = lane >> 4;
  const int m0 = blockIdx.x * 128;
  const int nb = blockIdx.y;           // 0..23
  const int seg = nb >> 3;             // 0=Q 1=K 2=V
  const int n0 = (nb & 7) * 128;
  const u16* __restrict__ Bt = (seg == 0) ? WqT : (seg == 1) ? WkT : WvT;
  const float* __restrict__ bias = (seg == 0) ? bq : (seg == 1) ? bk : bv;

  f32x4 acc[4][4];
#pragma unroll
  for (int i = 0; i < 4; i++)
#pragma unroll
    for (int j = 0; j < 4; j++) acc[i][j] = (f32x4){0.f, 0.f, 0.f, 0.f};

  const int srow = tid >> 3;                                    // 0..31
  const int sgz = ((tid >> 3) & 3) | (((tid >> 6) & 1) << 2);   // g(row)
  const int sc = (tid & 7) ^ sgz;
  const u16* ga0 = xb + (m0 + srow) * EMB + sc * 8;
  const u16* gb0 = Bt + (n0 + srow) * EMB + sc * 8;
  char* la0 = (char*)Al + w * 1024;    // wave-uniform LDS base
  char* lb0 = (char*)Bl + w * 1024;
  const int gfr = (lr & 3) | (((lr >> 3) & 1) << 2);

  for (int k0 = 0; k0 < EMB; k0 += 64) {
#pragma unroll
    for (int m = 0; m < 4; m++) {
      gload16(ga0 + (32 * m) * EMB + k0, la0 + m * 4096);
      gload16(gb0 + (32 * m) * EMB + k0, lb0 + m * 4096);
    }
    __syncthreads();
    u16x8 af[4][2], bfr[4][2];
#pragma unroll
    for (int hh = 0; hh < 2; hh++) {
      const int pc = ((hh * 4 + lg) ^ gfr) * 16;
#pragma unroll
      for (int mi = 0; mi < 4; mi++)
        af[mi][hh] =
            *(const u16x8*)((char*)Al + (wr * 64 + mi * 16 + lr) * 128 + pc);
#pragma unroll
      for (int ni = 0; ni < 4; ni++)
        bfr[ni][hh] =
            *(const u16x8*)((char*)Bl + (wc * 64 + ni * 16 + lr) * 128 + pc);
    }
    if (seg == 2) {  // V: C rows = m (lane holds 4 consecutive m)
#pragma unroll
      for (int hh = 0; hh < 2; hh++)
#pragma unroll
        for (int mi = 0; mi < 4; mi++)
#pragma unroll
          for (int ni = 0; ni < 4; ni++)
            acc[mi][ni] = __builtin_amdgcn_mfma_f32_16x16x32_bf16(
                asbf(af[mi][hh]), asbf(bfr[ni][hh]), acc[mi][ni], 0, 0, 0);
    } else {  // Q/K: swapped -> C rows = n (lane holds 4 consecutive n)
#pragma unroll
      for (int hh = 0; hh < 2; hh++)
#pragma unroll
        for (int mi = 0; mi < 4; mi++)
#pragma unroll
          for (int ni = 0; ni < 4; ni++)
            acc[mi][ni] = __builtin_amdgcn_mfma_f32_16x16x32_bf16(
                asbf(bfr[ni][hh]), asbf(af[mi][hh]), acc[mi][ni], 0, 0, 0);
    }
    __syncthreads();
  }

  const int b = m0 >> 11;  // batch (block never straddles)
  if (seg == 2) {  // Vt[(b*16+h)*64+d][t]: pack 4 consecutive t
#pragma unroll
    for (int ni = 0; ni < 4; ni++) {
      const int n = n0 + wc * 64 + ni * 16 + lr;
      const float bv_ = bias[n];
      const int h = n >> 6, d = n & 63;
      u16* vrow = Vt + (((b * NHEADS + h) * HD) + d) * TT;
#pragma unroll
      for (int mi = 0; mi < 4; mi++) {
        const int t0 = (m0 + wr * 64 + mi * 16 + lg * 4) & 2047;
        ushort4 pk;
        pk.x = cvt(acc[mi][ni][0] + bv_);
        pk.y = cvt(acc[mi][ni][1] + bv_);
        pk.z = cvt(acc[mi][ni][2] + bv_);
        pk.w = cvt(acc[mi][ni][3] + bv_);
        *(ushort4*)&vrow[t0] = pk;
      }
    }
  } else {  // Q/K [(b*16+h)*2048+t][d]: pack 4 consecutive d
    u16* __restrict__ dst = (seg == 0) ? Q : K;
    const float qs = 0.18033688011f;  // (1/8)*log2(e), exp2-domain scores
#pragma unroll
    for (int ni = 0; ni < 4; ni++) {
      const int nbase = n0 + wc * 64 + ni * 16 + lg * 4;
      const float4 bv4 = *(const float4*)&bias[nbase];
      const int h = nbase >> 6, d0 = nbase & 63;
#pragma unroll
      for (int mi = 0; mi < 4; mi++) {
        const int t = (m0 + wr * 64 + mi * 16 + lr) & 2047;
        float v0 = acc[mi][ni][0] + bv4.x;
        float v1 = acc[mi][ni][1] + bv4.y;
        float v2 = acc[mi][ni][2] + bv4.z;
        float v3 = acc[mi][ni][3] + bv4.w;
        if (seg == 0) { v0 *= qs; v1 *= qs; v2 *= qs; v3 *= qs; }
        ushort4 pk;
        pk.x = cvt(v0); pk.y = cvt(v1); pk.z = cvt(v2); pk.w = cvt(v3);
        *(ushort4*)&dst[(((b * NHEADS + h) * TT) + t) * HD + d0] = pk;
      }
    }
  }
}

// ---------- causal flash attention (r8 kernel, proven 44.5 us) ----------
// 512 thr / 8 waves, 64-row pairing (waves 0-3 hi=31-pair, 4-7 lo=pair),
// KVBLK=64, 2-phase double-buffered swizzled LDS staging, swapped QK^T
// in-register P, defer-max, exp2 domain.
__global__ __launch_bounds__(512) void k_attn(const u16* __restrict__ Q,
                                              const u16* __restrict__ Kg,
                                              const u16* __restrict__ Vt,
                                              u16* __restrict__ AO) {
  __shared__ u16 Kl[2][64 * 64];   // 8KB x2
  __shared__ u16 Vl[2][64 * 64];   // 8KB x2
  const int tid = threadIdx.x;
  const int lane = tid & 63;
  const int w = tid >> 6;          // 0..7
  const int lr = lane & 15, lg = lane >> 4;
  const int bh = blockIdx.x;       // 0..31
  const int pair = blockIdx.y;     // 0..15
  const int lo = pair, hi = 31 - pair;
  const int qblk = (w < 4) ? hi : lo;      // this wave's q-block
  const int myend = qblk;                  // last k-tile index for this wave
  const int q0 = qblk * 64 + (w & 3) * 16;
  const u16* __restrict__ Qh = Q + bh * TT * HD;
  const u16* __restrict__ Kh = Kg + bh * TT * HD;
  const u16* __restrict__ Vh = Vt + bh * HD * TT;

  const int srow = tid >> 3;  // 0..63
  const int sgz = ((tid >> 3) & 3) | (((tid >> 6) & 1) << 2);
  const int sc = (tid & 7) ^ sgz;

  u16x8 qf[2];
  qf[0] = *(const u16x8*)&Qh[(q0 + lr) * HD + lg * 8];
  qf[1] = *(const u16x8*)&Qh[(q0 + lr) * HD + 32 + lg * 8];

  f32x4 accO[4];
#pragma unroll
  for (int i = 0; i < 4; i++) accO[i] = (f32x4){0.f, 0.f, 0.f, 0.f};
  float mst = -__builtin_inff();  // per-lane: running max of row q0+lr
  float lsum = 0.f;               // per-lane partial denominator

  const int nkt = hi + 1;  // block-uniform loop count

  gload16(Kh + srow * HD + sc * 8, (char*)Kl[0] + w * 1024);
  gload16(Vh + srow * TT + sc * 8, (char*)Vl[0] + w * 1024);
  __syncthreads();  // drains vmcnt

  for (int kt = 0; kt < nkt; ++kt) {
    const int k0 = kt * 64;
    const int cur = kt & 1;
    if (kt + 1 < nkt) {  // issue next-tile loads BEFORE compute (2-phase)
      const int kn = k0 + 64;
      gload16(Kh + (kn + srow) * HD + sc * 8, (char*)Kl[cur ^ 1] + w * 1024);
      gload16(Vh + srow * TT + kn + sc * 8, (char*)Vl[cur ^ 1] + w * 1024);
    }
    if (kt <= myend) {  // wave-uniform: lo-waves idle past their diagonal
      const char* Kc = (const char*)Kl[cur];
      const char* Vc = (const char*)Vl[cur];

      f32x4 s[4];
#pragma unroll
      for (int n = 0; n < 4; n++) s[n] = (f32x4){0.f, 0.f, 0.f, 0.f};
      __builtin_amdgcn_s_setprio(1);
#pragma unroll
      for (int n = 0; n < 4; n++) {
        // permuted K-row: lane's 16 score cols == PV A-frag slots
        const int kr =
            (lr & 3) + ((n & 1) << 2) + ((lr >> 2) << 3) + ((n >> 1) << 5);
        const int gg = (kr & 3) | (((kr >> 3) & 1) << 2);
#pragma unroll
        for (int dh = 0; dh < 2; dh++) {
          const int bo = ((dh * 4 + lg) ^ gg) << 4;
          u16x8 kf = *(const u16x8*)(Kc + kr * 128 + bo);
          s[n] = __builtin_amdgcn_mfma_f32_16x16x32_bf16(asbf(kf), asbf(qf[dh]),
                                                         s[n], 0, 0, 0);
        }
      }
      __builtin_amdgcn_s_setprio(0);
      if (kt == myend) {  // diagonal tile: causal mask (col > my q-row)
        const int rowq = q0 + lr;
#pragma unroll
        for (int n = 0; n < 4; n++) {
          const int cb = k0 + ((n & 1) << 2) + (lg << 3) + ((n >> 1) << 5);
#pragma unroll
          for (int r = 0; r < 4; r++)
            if (cb + r > rowq) s[n][r] = -__builtin_inff();
        }
      }
      // lane-local row max over this tile's 16 cols
      float m01 = fmaxf(fmaxf(s[0][0], s[0][1]), fmaxf(s[0][2], s[0][3]));
      float m1 = fmaxf(fmaxf(s[1][0], s[1][1]), fmaxf(s[1][2], s[1][3]));
      float m2 = fmaxf(fmaxf(s[2][0], s[2][1]), fmaxf(s[2][2], s[2][3]));
      float m3 = fmaxf(fmaxf(s[3][0], s[3][1]), fmaxf(s[3][2], s[3][3]));
      float lmax = fmaxf(fmaxf(m01, m1), fmaxf(m2, m3));
      // defer-max (log2 domain, THR=11 bits). -inf tile0 forces rescale.
      if (!__all(lmax - mst <= 11.0f)) {
        float rm = lmax;
        rm = fmaxf(rm, __shfl_xor(rm, 16));
        rm = fmaxf(rm, __shfl_xor(rm, 32));
        float mnew = fmaxf(mst, rm);
        float corr = exp2f(mst - mnew);
        lsum *= corr;
        mst = mnew;
#pragma unroll
        for (int r = 0; r < 4; r++) {  // corr for accO's q-row (lg*4+r)
          float ca = __shfl(corr, 20 * lg + r);
#pragma unroll
          for (int dt = 0; dt < 4; dt++) accO[dt][r] *= ca;
        }
      }
      // P in-register: p[n][r] are exactly PV A-frag slots
      float p[4][4];
      float ls = 0.f;
#pragma unroll
      for (int n = 0; n < 4; n++)
#pragma unroll
        for (int r = 0; r < 4; r++) {
          p[n][r] = exp2f(s[n][r] - mst);
          ls += p[n][r];
        }
      lsum += ls;
      u16x8 a1, a2;
#pragma unroll
      for (int r = 0; r < 4; r++) {
        a1[r] = cvt(p[0][r]);
        a1[4 + r] = cvt(p[1][r]);
        a2[r] = cvt(p[2][r]);
        a2[4 + r] = cvt(p[3][r]);
      }
      __builtin_amdgcn_s_setprio(1);
#pragma unroll
      for (int dt = 0; dt < 4; dt++) {
        const int row = dt * 16 + lr;
        const int gg = (row & 3) | (((row >> 3) & 1) << 2);
        const int bo0 = ((lg ^ gg) << 4);
        const int bo1 = (((4 + lg) ^ gg) << 4);
        u16x8 vf0 = *(const u16x8*)(Vc + row * 128 + bo0);
        u16x8 vf1 = *(const u16x8*)(Vc + row * 128 + bo1);
        accO[dt] = __builtin_amdgcn_mfma_f32_16x16x32_bf16(asbf(a1), asbf(vf0),
                                                           accO[dt], 0, 0, 0);
        accO[dt] = __builtin_amdgcn_mfma_f32_16x16x32_bf16(asbf(a2), asbf(vf1),
                                                           accO[dt], 0, 0, 0);
      }
      __builtin_amdgcn_s_setprio(0);
    }
    __syncthreads();  // drains vmcnt: next buf staged; cur free to overwrite
  }
  // denominator: reduce the 4 lanes sharing this q-row, then redistribute
  float t = lsum;
  t += __shfl_xor(t, 16);
  t += __shfl_xor(t, 32);
  float rinv = 1.0f / t;
  float ra[4];
#pragma unroll
  for (int r = 0; r < 4; r++) ra[r] = __shfl(rinv, 20 * lg + r);
  const int b = bh >> 4, h = bh & 15;
#pragma unroll
  for (int dt = 0; dt < 4; dt++)
#pragma unroll
    for (int r = 0; r < 4; r++) {
      const int row = q0 + lg * 4 + r;
      const int d = h * 64 + dt * 16 + lr;
      AO[(b * TT + row) * EMB + d] = cvt(accO[dt][r] * ra[r]);
    }
}

// ---------- output projection GEMM (swapped frags, float4 epilogue) -------
__global__ __launch_bounds__(256) void k_gemm_out(const u16* __restrict__ AO,
                                                  const u16* __restrict__ WoT,
                                                  const float* __restrict__ bo,
                                                  float* __restrict__ out) {
  __shared__ u16 Al[128 * 64];
  __shared__ u16 Bl[128 * 64];
  const int tid = threadIdx.x;
  const int lane = tid & 63;
  const int w = tid >> 6;
  const int wr = w >> 1, wc = w & 1;
  const int lr = lane & 15, lg = lane >> 4;
  const int m0 = blockIdx.x * 128;
  const int n0 = blockIdx.y * 128;

  f32x4 acc[4][4];
#pragma unroll
  for (int i = 0; i < 4; i++)
#pragma unroll
    for (int j = 0; j < 4; j++) acc[i][j] = (f32x4){0.f, 0.f, 0.f, 0.f};

  const int srow = tid >> 3;
  const int sgz = ((tid >> 3) & 3) | (((tid >> 6) & 1) << 2);
  const int sc = (tid & 7) ^ sgz;
  const u16* ga0 = AO + (m0 + srow) * EMB + sc * 8;
  const u16* gb0 = WoT + (n0 + srow) * EMB + sc * 8;
  char* la0 = (char*)Al + w * 1024;
  char* lb0 = (char*)Bl + w * 1024;
  const int gfr = (lr & 3) | (((lr >> 3) & 1) << 2);

  for (int k0 = 0; k0 < EMB; k0 += 64) {
#pragma unroll
    for (int m = 0; m < 4; m++) {
      gload16(ga0 + (32 * m) * EMB + k0, la0 + m * 4096);
      gload16(gb0 + (32 * m) * EMB + k0, lb0 + m * 4096);
    }
    __syncthreads();
    u16x8 af[4][2], bfr[4][2];
#pragma unroll
    for (int hh = 0; hh < 2; hh++) {
      const int pc = ((hh * 4 + lg) ^ gfr) * 16;
#pragma unroll
      for (int mi = 0; mi < 4; mi++)
        af[mi][hh] =
            *(const u16x8*)((char*)Al + (wr * 64 + mi * 16 + lr) * 128 + pc);
#pragma unroll
      for (int ni = 0; ni < 4; ni++)
        bfr[ni][hh] =
            *(const u16x8*)((char*)Bl + (wc * 64 + ni * 16 + lr) * 128 + pc);
    }
    // swapped: C rows = n (lane holds 4 consecutive n at fixed m)
#pragma unroll
    for (int hh = 0; hh < 2; hh++)
#pragma unroll
      for (int mi = 0; mi < 4; mi++)
#pragma unroll
        for (int ni = 0; ni < 4; ni++)
          acc[mi][ni] = __builtin_amdgcn_mfma_f32_16x16x32_bf16(
              asbf(bfr[ni][hh]), asbf(af[mi][hh]), acc[mi][ni], 0, 0, 0);
    __syncthreads();
  }

#pragma unroll
  for (int ni = 0; ni < 4; ni++) {
    const int nbase = n0 + wc * 64 + ni * 16 + lg * 4;
    const float4 bv4 = *(const float4*)&bo[nbase];
#pragma unroll
    for (int mi = 0; mi < 4; mi++) {
      const int m = m0 + wr * 64 + mi * 16 + lr;
      float4 v;
      v.x = acc[mi][ni][0] + bv4.x;
      v.y = acc[mi][ni][1] + bv4.y;
      v.z = acc[mi][ni][2] + bv4.z;
      v.w = acc[mi][ni][3] + bv4.w;
      *(float4*)&out[m * EMB + nbase] = v;
    }
  }
}

// ---------- launch ----------
extern "C" void kernel_launch(void* const* d_in, const int* in_sizes, int n_in,
                              void* d_out, int out_size, void* d_ws,
                              size_t ws_size, hipStream_t stream) {
  const float* x = (const float*)d_in[0];
  const float* Wq = (const float*)d_in[1];
  const float* bq = (const float*)d_in[2];
  const float* Wk = (const float*)d_in[3];
  const float* bk = (const float*)d_in[4];
  const float* Wv = (const float*)d_in[5];
  const float* bv = (const float*)d_in[6];
  const float* Wo = (const float*)d_in[7];
  const float* bo = (const float*)d_in[8];
  float* out = (float*)d_out;

  char* ws = (char*)d_ws;
  u16* xb = (u16*)ws;                      // 8 MB (reused as AO)
  u16* WqT = (u16*)(ws + (8u << 20));      // 2 MB
  u16* WkT = (u16*)(ws + (10u << 20));     // 2 MB
  u16* WvT = (u16*)(ws + (12u << 20));     // 2 MB
  u16* WoT = (u16*)(ws + (14u << 20));     // 2 MB
  u16* Qb = (u16*)(ws + (16u << 20));      // 8 MB
  u16* Kb = (u16*)(ws + (24u << 20));      // 8 MB
  u16* Vtb = (u16*)(ws + (32u << 20));     // 8 MB (total 40 MB)
  u16* AO = xb;

  k_prep<<<6144, 256, 0, stream>>>(x, xb, Wq, Wk, Wv, Wo, WqT, WkT, WvT, WoT);
  k_gemm_qkv<<<dim3(32, 24), 256, 0, stream>>>(xb, WqT, WkT, WvT, bq, bk, bv,
                                               Qb, Kb, Vtb);
  k_attn<<<dim3(32, 16), 512, 0, stream>>>(Qb, Kb, Vtb, AO);
  k_gemm_out<<<dim3(32, 8), 256, 0, stream>>>(AO, WoT, bo, out);
}

// Round 12
// 126.173 us; speedup vs baseline: 1.0490x; 1.0490x over previous
//
#include <hip/hip_runtime.h>

typedef unsigned short u16;
typedef u16 u16x8 __attribute__((ext_vector_type(8)));
typedef __bf16 bf16x8 __attribute__((ext_vector_type(8)));
typedef float f32x4 __attribute__((ext_vector_type(4)));

#define EMB 1024
#define TT 2048
#define BB 2
#define NHEADS 16
#define HD 64
#define MTOT (BB * TT)  // 4096

// ---------- helpers ----------
__device__ __forceinline__ u16 cvt(float f) {  // native f32->bf16 (RTNE)
  return __builtin_bit_cast(u16, (__bf16)f);
}

__device__ __forceinline__ bf16x8 asbf(u16x8 v) {
  return __builtin_bit_cast(bf16x8, v);
}

__device__ __forceinline__ void gload16(const void* g, void* l) {
  __builtin_amdgcn_global_load_lds(
      (const __attribute__((address_space(1))) void*)g,
      (__attribute__((address_space(3))) void*)l, 16, 0, 0);
}

// ---------- fused prep: x->bf16 + 4x W transpose->bf16, one launch ----------
__global__ __launch_bounds__(256) void k_prep(
    const float* __restrict__ x, u16* __restrict__ xb,
    const float* __restrict__ W0, const float* __restrict__ W1,
    const float* __restrict__ W2, const float* __restrict__ W3,
    u16* __restrict__ T0, u16* __restrict__ T1, u16* __restrict__ T2,
    u16* __restrict__ T3) {
  __shared__ float tile[32][33];
  const int bid = blockIdx.x;
  const int tid = threadIdx.x;
  if (bid >= 4096) {  // x conversion: 2048 blocks x 2048 elems
    int i = (bid - 4096) * 256 + tid;
    float4 a = ((const float4*)x)[i * 2];
    float4 b = ((const float4*)x)[i * 2 + 1];
    u16x8 o;
    o[0] = cvt(a.x); o[1] = cvt(a.y); o[2] = cvt(a.z); o[3] = cvt(a.w);
    o[4] = cvt(b.x); o[5] = cvt(b.y); o[6] = cvt(b.z); o[7] = cvt(b.w);
    ((u16x8*)xb)[i] = o;
    return;
  }
  const int z = bid >> 10;  // which W
  const float* __restrict__ W = (z == 0) ? W0 : (z == 1) ? W1 : (z == 2) ? W2 : W3;
  u16* __restrict__ Wt = (z == 0) ? T0 : (z == 1) ? T1 : (z == 2) ? T2 : T3;
  const int b = bid & 1023;
  const int bx = (b & 31) * 32, by = (b >> 5) * 32;
  const int tx = tid & 31;
  const int ty = tid >> 5;  // 0..7
#pragma unroll
  for (int r = ty; r < 32; r += 8) tile[r][tx] = W[(by + r) * EMB + bx + tx];
  __syncthreads();
  // vectorized transposed store: each thread packs 2 cols into one dword
  const int tx2 = tid & 15;
  const int ty2 = tid >> 4;  // 0..15
#pragma unroll
  for (int r = ty2; r < 32; r += 16) {
    unsigned v = (unsigned)cvt(tile[2 * tx2][r]) |
                 ((unsigned)cvt(tile[2 * tx2 + 1][r]) << 16);
    *(unsigned*)&Wt[(bx + r) * EMB + by + 2 * tx2] = v;
  }
}

// ---------- fused QKV GEMM (BK=32, double-buffered 2-phase prefetch) ------
// Uniform mfma(A,B) (no MFMA-loop branch -> low VGPR). Epilogue-only branch:
// V packs 4 consecutive t (ushort4); Q/K scalar stores (r10-proven).
__global__ __launch_bounds__(256) void k_gemm_qkv(
    const u16* __restrict__ xb, const u16* __restrict__ WqT,
    const u16* __restrict__ WkT, const u16* __restrict__ WvT,
    const float* __restrict__ bq, const float* __restrict__ bk,
    const float* __restrict__ bv, u16* __restrict__ Q, u16* __restrict__ K,
    u16* __restrict__ Vt) {
  __shared__ u16 Al[2][128 * 32];  // 8KB x2 (m97 64B-row layout)
  __shared__ u16 Bl[2][128 * 32];
  const int tid = threadIdx.x;
  const int lane = tid & 63;
  const int w = tid >> 6;
  const int wr = w >> 1, wc = w & 1;
  const int lr = lane & 15, lg = lane >> 4;
  const int m0 = blockIdx.x * 128;
  const int nb = blockIdx.y;           // 0..23
  const int seg = nb >> 3;             // 0=Q 1=K 2=V
  const int n0 = (nb & 7) * 128;
  const u16* __restrict__ Bt = (seg == 0) ? WqT : (seg == 1) ? WkT : WvT;
  const float* __restrict__ bias = (seg == 0) ? bq : (seg == 1) ? bk : bv;

  f32x4 acc[4][4];
#pragma unroll
  for (int i = 0; i < 4; i++)
#pragma unroll
    for (int j = 0; j < 4; j++) acc[i][j] = (f32x4){0.f, 0.f, 0.f, 0.f};

  // staging: thread t -> row t>>2 (0..63), 16B chunk t&3; wave block = 1KB
  const int srow = tid >> 2;
  const int scol = (tid & 3) * 8;
  const u16* ga0 = xb + (m0 + srow) * EMB + scol;
  const u16* gb0 = Bt + (n0 + srow) * EMB + scol;
  const int lofs = w * 1024;  // wave-uniform LDS byte base

  // prologue: stage k=0 into buf 0
  gload16(ga0, (char*)Al[0] + lofs);
  gload16(ga0 + 64 * EMB, (char*)Al[0] + lofs + 4096);
  gload16(gb0, (char*)Bl[0] + lofs);
  gload16(gb0 + 64 * EMB, (char*)Bl[0] + lofs + 4096);
  __syncthreads();

  int cur = 0;
  for (int k0 = 0; k0 < EMB; k0 += 32, cur ^= 1) {
    if (k0 + 32 < EMB) {  // issue next-tile loads BEFORE compute (2-phase)
      const int kn = k0 + 32;
      gload16(ga0 + kn, (char*)Al[cur ^ 1] + lofs);
      gload16(ga0 + 64 * EMB + kn, (char*)Al[cur ^ 1] + lofs + 4096);
      gload16(gb0 + kn, (char*)Bl[cur ^ 1] + lofs);
      gload16(gb0 + 64 * EMB + kn, (char*)Bl[cur ^ 1] + lofs + 4096);
    }
    u16x8 af[4], bfr[4];
#pragma unroll
    for (int mi = 0; mi < 4; mi++)
      af[mi] = *(const u16x8*)&Al[cur][(wr * 64 + mi * 16 + lr) * 32 + lg * 8];
#pragma unroll
    for (int ni = 0; ni < 4; ni++)
      bfr[ni] = *(const u16x8*)&Bl[cur][(wc * 64 + ni * 16 + lr) * 32 + lg * 8];
#pragma unroll
    for (int mi = 0; mi < 4; mi++)
#pragma unroll
      for (int ni = 0; ni < 4; ni++)
        acc[mi][ni] = __builtin_amdgcn_mfma_f32_16x16x32_bf16(
            asbf(af[mi]), asbf(bfr[ni]), acc[mi][ni], 0, 0, 0);
    __syncthreads();  // drains vmcnt: next buf staged; cur free to overwrite
  }

  const int b = m0 >> 11;  // batch (block never straddles)
  if (seg == 2) {  // Vt[(b*16+h)*64+d][t]: 4 consecutive t -> ushort4
#pragma unroll
    for (int ni = 0; ni < 4; ni++) {
      const int n = n0 + wc * 64 + ni * 16 + lr;
      const float bv_ = bias[n];
      const int h = n >> 6, d = n & 63;
      u16* vrow = Vt + (((b * NHEADS + h) * HD) + d) * TT;
#pragma unroll
      for (int mi = 0; mi < 4; mi++) {
        const int t0 = (m0 + wr * 64 + mi * 16 + lg * 4) & 2047;
        ushort4 pk;
        pk.x = cvt(acc[mi][ni][0] + bv_);
        pk.y = cvt(acc[mi][ni][1] + bv_);
        pk.z = cvt(acc[mi][ni][2] + bv_);
        pk.w = cvt(acc[mi][ni][3] + bv_);
        *(ushort4*)&vrow[t0] = pk;
      }
    }
  } else {  // Q/K [(b*16+h)*2048+t][d]: scalar stores (r10-proven)
    u16* __restrict__ dst = (seg == 0) ? Q : K;
    const float qs = (seg == 0) ? 0.18033688011f : 1.0f;  // (1/8)*log2(e)
#pragma unroll
    for (int mi = 0; mi < 4; mi++) {
      const int lmb = wr * 64 + mi * 16 + lg * 4;
#pragma unroll
      for (int ni = 0; ni < 4; ni++) {
        const int n = n0 + wc * 64 + ni * 16 + lr;
        const float bv_ = bias[n];
        const int h = n >> 6, d = n & 63;
#pragma unroll
        for (int r = 0; r < 4; r++) {
          const int t = (m0 + lmb + r) & 2047;
          float v = (acc[mi][ni][r] + bv_) * qs;
          dst[(((b * NHEADS + h) * TT) + t) * HD + d] = cvt(v);
        }
      }
    }
  }
}

// ---------- causal flash attention (r8 kernel, proven 44.5 us) ----------
__global__ __launch_bounds__(512) void k_attn(const u16* __restrict__ Q,
                                              const u16* __restrict__ Kg,
                                              const u16* __restrict__ Vt,
                                              u16* __restrict__ AO) {
  __shared__ u16 Kl[2][64 * 64];   // 8KB x2
  __shared__ u16 Vl[2][64 * 64];   // 8KB x2
  const int tid = threadIdx.x;
  const int lane = tid & 63;
  const int w = tid >> 6;          // 0..7
  const int lr = lane & 15, lg = lane >> 4;
  const int bh = blockIdx.x;       // 0..31
  const int pair = blockIdx.y;     // 0..15
  const int lo = pair, hi = 31 - pair;
  const int qblk = (w < 4) ? hi : lo;      // this wave's q-block
  const int myend = qblk;                  // last k-tile index for this wave
  const int q0 = qblk * 64 + (w & 3) * 16;
  const u16* __restrict__ Qh = Q + bh * TT * HD;
  const u16* __restrict__ Kh = Kg + bh * TT * HD;
  const u16* __restrict__ Vh = Vt + bh * HD * TT;

  const int srow = tid >> 3;  // 0..63
  const int sgz = ((tid >> 3) & 3) | (((tid >> 6) & 1) << 2);
  const int sc = (tid & 7) ^ sgz;

  u16x8 qf[2];
  qf[0] = *(const u16x8*)&Qh[(q0 + lr) * HD + lg * 8];
  qf[1] = *(const u16x8*)&Qh[(q0 + lr) * HD + 32 + lg * 8];

  f32x4 accO[4];
#pragma unroll
  for (int i = 0; i < 4; i++) accO[i] = (f32x4){0.f, 0.f, 0.f, 0.f};
  float mst = -__builtin_inff();  // per-lane: running max of row q0+lr
  float lsum = 0.f;               // per-lane partial denominator

  const int nkt = hi + 1;  // block-uniform loop count

  gload16(Kh + srow * HD + sc * 8, (char*)Kl[0] + w * 1024);
  gload16(Vh + srow * TT + sc * 8, (char*)Vl[0] + w * 1024);
  __syncthreads();  // drains vmcnt

  for (int kt = 0; kt < nkt; ++kt) {
    const int k0 = kt * 64;
    const int cur = kt & 1;
    if (kt + 1 < nkt) {  // issue next-tile loads BEFORE compute (2-phase)
      const int kn = k0 + 64;
      gload16(Kh + (kn + srow) * HD + sc * 8, (char*)Kl[cur ^ 1] + w * 1024);
      gload16(Vh + srow * TT + kn + sc * 8, (char*)Vl[cur ^ 1] + w * 1024);
    }
    if (kt <= myend) {  // wave-uniform: lo-waves idle past their diagonal
      const char* Kc = (const char*)Kl[cur];
      const char* Vc = (const char*)Vl[cur];

      f32x4 s[4];
#pragma unroll
      for (int n = 0; n < 4; n++) s[n] = (f32x4){0.f, 0.f, 0.f, 0.f};
      __builtin_amdgcn_s_setprio(1);
#pragma unroll
      for (int n = 0; n < 4; n++) {
        // permuted K-row: lane's 16 score cols == PV A-frag slots
        const int kr =
            (lr & 3) + ((n & 1) << 2) + ((lr >> 2) << 3) + ((n >> 1) << 5);
        const int gg = (kr & 3) | (((kr >> 3) & 1) << 2);
#pragma unroll
        for (int dh = 0; dh < 2; dh++) {
          const int bo = ((dh * 4 + lg) ^ gg) << 4;
          u16x8 kf = *(const u16x8*)(Kc + kr * 128 + bo);
          s[n] = __builtin_amdgcn_mfma_f32_16x16x32_bf16(asbf(kf), asbf(qf[dh]),
                                                         s[n], 0, 0, 0);
        }
      }
      __builtin_amdgcn_s_setprio(0);
      if (kt == myend) {  // diagonal tile: causal mask (col > my q-row)
        const int rowq = q0 + lr;
#pragma unroll
        for (int n = 0; n < 4; n++) {
          const int cb = k0 + ((n & 1) << 2) + (lg << 3) + ((n >> 1) << 5);
#pragma unroll
          for (int r = 0; r < 4; r++)
            if (cb + r > rowq) s[n][r] = -__builtin_inff();
        }
      }
      // lane-local row max over this tile's 16 cols
      float m01 = fmaxf(fmaxf(s[0][0], s[0][1]), fmaxf(s[0][2], s[0][3]));
      float m1 = fmaxf(fmaxf(s[1][0], s[1][1]), fmaxf(s[1][2], s[1][3]));
      float m2 = fmaxf(fmaxf(s[2][0], s[2][1]), fmaxf(s[2][2], s[2][3]));
      float m3 = fmaxf(fmaxf(s[3][0], s[3][1]), fmaxf(s[3][2], s[3][3]));
      float lmax = fmaxf(fmaxf(m01, m1), fmaxf(m2, m3));
      // defer-max (log2 domain, THR=11 bits). -inf tile0 forces rescale.
      if (!__all(lmax - mst <= 11.0f)) {
        float rm = lmax;
        rm = fmaxf(rm, __shfl_xor(rm, 16));
        rm = fmaxf(rm, __shfl_xor(rm, 32));
        float mnew = fmaxf(mst, rm);
        float corr = exp2f(mst - mnew);
        lsum *= corr;
        mst = mnew;
#pragma unroll
        for (int r = 0; r < 4; r++) {  // corr for accO's q-row (lg*4+r)
          float ca = __shfl(corr, 20 * lg + r);
#pragma unroll
          for (int dt = 0; dt < 4; dt++) accO[dt][r] *= ca;
        }
      }
      // P in-register: p[n][r] are exactly PV A-frag slots
      float p[4][4];
      float ls = 0.f;
#pragma unroll
      for (int n = 0; n < 4; n++)
#pragma unroll
        for (int r = 0; r < 4; r++) {
          p[n][r] = exp2f(s[n][r] - mst);
          ls += p[n][r];
        }
      lsum += ls;
      u16x8 a1, a2;
#pragma unroll
      for (int r = 0; r < 4; r++) {
        a1[r] = cvt(p[0][r]);
        a1[4 + r] = cvt(p[1][r]);
        a2[r] = cvt(p[2][r]);
        a2[4 + r] = cvt(p[3][r]);
      }
      __builtin_amdgcn_s_setprio(1);
#pragma unroll
      for (int dt = 0; dt < 4; dt++) {
        const int row = dt * 16 + lr;
        const int gg = (row & 3) | (((row >> 3) & 1) << 2);
        const int bo0 = ((lg ^ gg) << 4);
        const int bo1 = (((4 + lg) ^ gg) << 4);
        u16x8 vf0 = *(const u16x8*)(Vc + row * 128 + bo0);
        u16x8 vf1 = *(const u16x8*)(Vc + row * 128 + bo1);
        accO[dt] = __builtin_amdgcn_mfma_f32_16x16x32_bf16(asbf(a1), asbf(vf0),
                                                           accO[dt], 0, 0, 0);
        accO[dt] = __builtin_amdgcn_mfma_f32_16x16x32_bf16(asbf(a2), asbf(vf1),
                                                           accO[dt], 0, 0, 0);
      }
      __builtin_amdgcn_s_setprio(0);
    }
    __syncthreads();  // drains vmcnt: next buf staged; cur free to overwrite
  }
  // denominator: reduce the 4 lanes sharing this q-row, then redistribute
  float t = lsum;
  t += __shfl_xor(t, 16);
  t += __shfl_xor(t, 32);
  float rinv = 1.0f / t;
  float ra[4];
#pragma unroll
  for (int r = 0; r < 4; r++) ra[r] = __shfl(rinv, 20 * lg + r);
  const int b = bh >> 4, h = bh & 15;
#pragma unroll
  for (int dt = 0; dt < 4; dt++)
#pragma unroll
    for (int r = 0; r < 4; r++) {
      const int row = q0 + lg * 4 + r;
      const int d = h * 64 + dt * 16 + lr;
      AO[(b * TT + row) * EMB + d] = cvt(accO[dt][r] * ra[r]);
    }
}

// ---------- output projection GEMM (swapped frags, float4 epilogue) -------
__global__ __launch_bounds__(256) void k_gemm_out(const u16* __restrict__ AO,
                                                  const u16* __restrict__ WoT,
                                                  const float* __restrict__ bo,
                                                  float* __restrict__ out) {
  __shared__ u16 Al[128 * 64];
  __shared__ u16 Bl[128 * 64];
  const int tid = threadIdx.x;
  const int lane = tid & 63;
  const int w = tid >> 6;
  const int wr = w >> 1, wc = w & 1;
  const int lr = lane & 15, lg = lane >> 4;
  const int m0 = blockIdx.x * 128;
  const int n0 = blockIdx.y * 128;

  f32x4 acc[4][4];
#pragma unroll
  for (int i = 0; i < 4; i++)
#pragma unroll
    for (int j = 0; j < 4; j++) acc[i][j] = (f32x4){0.f, 0.f, 0.f, 0.f};

  const int srow = tid >> 3;
  const int sgz = ((tid >> 3) & 3) | (((tid >> 6) & 1) << 2);
  const int sc = (tid & 7) ^ sgz;
  const u16* ga0 = AO + (m0 + srow) * EMB + sc * 8;
  const u16* gb0 = WoT + (n0 + srow) * EMB + sc * 8;
  char* la0 = (char*)Al + w * 1024;
  char* lb0 = (char*)Bl + w * 1024;
  const int gfr = (lr & 3) | (((lr >> 3) & 1) << 2);

  for (int k0 = 0; k0 < EMB; k0 += 64) {
#pragma unroll
    for (int m = 0; m < 4; m++) {
      gload16(ga0 + (32 * m) * EMB + k0, la0 + m * 4096);
      gload16(gb0 + (32 * m) * EMB + k0, lb0 + m * 4096);
    }
    __syncthreads();
    u16x8 af[4][2], bfr[4][2];
#pragma unroll
    for (int hh = 0; hh < 2; hh++) {
      const int pc = ((hh * 4 + lg) ^ gfr) * 16;
#pragma unroll
      for (int mi = 0; mi < 4; mi++)
        af[mi][hh] =
            *(const u16x8*)((char*)Al + (wr * 64 + mi * 16 + lr) * 128 + pc);
#pragma unroll
      for (int ni = 0; ni < 4; ni++)
        bfr[ni][hh] =
            *(const u16x8*)((char*)Bl + (wc * 64 + ni * 16 + lr) * 128 + pc);
    }
    // swapped: C rows = n (lane holds 4 consecutive n at fixed m)
#pragma unroll
    for (int hh = 0; hh < 2; hh++)
#pragma unroll
      for (int mi = 0; mi < 4; mi++)
#pragma unroll
        for (int ni = 0; ni < 4; ni++)
          acc[mi][ni] = __builtin_amdgcn_mfma_f32_16x16x32_bf16(
              asbf(bfr[ni][hh]), asbf(af[mi][hh]), acc[mi][ni], 0, 0, 0);
    __syncthreads();
  }

#pragma unroll
  for (int ni = 0; ni < 4; ni++) {
    const int nbase = n0 + wc * 64 + ni * 16 + lg * 4;
    const float4 bv4 = *(const float4*)&bo[nbase];
#pragma unroll
    for (int mi = 0; mi < 4; mi++) {
      const int m = m0 + wr * 64 + mi * 16 + lr;
      float4 v;
      v.x = acc[mi][ni][0] + bv4.x;
      v.y = acc[mi][ni][1] + bv4.y;
      v.z = acc[mi][ni][2] + bv4.z;
      v.w = acc[mi][ni][3] + bv4.w;
      *(float4*)&out[m * EMB + nbase] = v;
    }
  }
}

// ---------- launch ----------
extern "C" void kernel_launch(void* const* d_in, const int* in_sizes, int n_in,
                              void* d_out, int out_size, void* d_ws,
                              size_t ws_size, hipStream_t stream) {
  const float* x = (const float*)d_in[0];
  const float* Wq = (const float*)d_in[1];
  const float* bq = (const float*)d_in[2];
  const float* Wk = (const float*)d_in[3];
  const float* bk = (const float*)d_in[4];
  const float* Wv = (const float*)d_in[5];
  const float* bv = (const float*)d_in[6];
  const float* Wo = (const float*)d_in[7];
  const float* bo = (const float*)d_in[8];
  float* out = (float*)d_out;

  char* ws = (char*)d_ws;
  u16* xb = (u16*)ws;                      // 8 MB (reused as AO)
  u16* WqT = (u16*)(ws + (8u << 20));      // 2 MB
  u16* WkT = (u16*)(ws + (10u << 20));     // 2 MB
  u16* WvT = (u16*)(ws + (12u << 20));     // 2 MB
  u16* WoT = (u16*)(ws + (14u << 20));     // 2 MB
  u16* Qb = (u16*)(ws + (16u << 20));      // 8 MB
  u16* Kb = (u16*)(ws + (24u << 20));      // 8 MB
  u16* Vtb = (u16*)(ws + (32u << 20));     // 8 MB (total 40 MB)
  u16* AO = xb;

  k_prep<<<6144, 256, 0, stream>>>(x, xb, Wq, Wk, Wv, Wo, WqT, WkT, WvT, WoT);
  k_gemm_qkv<<<dim3(32, 24), 256, 0, stream>>>(xb, WqT, WkT, WvT, bq, bk, bv,
                                               Qb, Kb, Vtb);
  k_attn<<<dim3(32, 16), 512, 0, stream>>>(Qb, Kb, Vtb, AO);
  k_gemm_out<<<dim3(32, 8), 256, 0, stream>>>(AO, WoT, bo, out);
}

// Round 13
// 119.216 us; speedup vs baseline: 1.1102x; 1.0584x over previous
//
#include <hip/hip_runtime.h>

typedef unsigned short u16;
typedef u16 u16x8 __attribute__((ext_vector_type(8)));
typedef __bf16 bf16x8 __attribute__((ext_vector_type(8)));
typedef float f32x4 __attribute__((ext_vector_type(4)));

#define EMB 1024
#define TT 2048
#define BB 2
#define NHEADS 16
#define HD 64
#define MTOT (BB * TT)  // 4096

// ---------- helpers ----------
__device__ __forceinline__ u16 cvt(float f) {  // native f32->bf16 (RTNE)
  return __builtin_bit_cast(u16, (__bf16)f);
}

__device__ __forceinline__ bf16x8 asbf(u16x8 v) {
  return __builtin_bit_cast(bf16x8, v);
}

__device__ __forceinline__ void gload16(const void* g, void* l) {
  __builtin_amdgcn_global_load_lds(
      (const __attribute__((address_space(1))) void*)g,
      (__attribute__((address_space(3))) void*)l, 16, 0, 0);
}

// ---------- fused prep: x->bf16 + 4x W transpose->bf16, one launch ----------
__global__ __launch_bounds__(256) void k_prep(
    const float* __restrict__ x, u16* __restrict__ xb,
    const float* __restrict__ W0, const float* __restrict__ W1,
    const float* __restrict__ W2, const float* __restrict__ W3,
    u16* __restrict__ T0, u16* __restrict__ T1, u16* __restrict__ T2,
    u16* __restrict__ T3) {
  __shared__ float tile[32][33];
  const int bid = blockIdx.x;
  const int tid = threadIdx.x;
  if (bid >= 4096) {  // x conversion: 2048 blocks x 2048 elems
    int i = (bid - 4096) * 256 + tid;
    float4 a = ((const float4*)x)[i * 2];
    float4 b = ((const float4*)x)[i * 2 + 1];
    u16x8 o;
    o[0] = cvt(a.x); o[1] = cvt(a.y); o[2] = cvt(a.z); o[3] = cvt(a.w);
    o[4] = cvt(b.x); o[5] = cvt(b.y); o[6] = cvt(b.z); o[7] = cvt(b.w);
    ((u16x8*)xb)[i] = o;
    return;
  }
  const int z = bid >> 10;  // which W
  const float* __restrict__ W = (z == 0) ? W0 : (z == 1) ? W1 : (z == 2) ? W2 : W3;
  u16* __restrict__ Wt = (z == 0) ? T0 : (z == 1) ? T1 : (z == 2) ? T2 : T3;
  const int b = bid & 1023;
  const int bx = (b & 31) * 32, by = (b >> 5) * 32;
  const int tx = tid & 31;
  const int ty = tid >> 5;  // 0..7
#pragma unroll
  for (int r = ty; r < 32; r += 8) tile[r][tx] = W[(by + r) * EMB + bx + tx];
  __syncthreads();
  // vectorized transposed store: each thread packs 2 cols into one dword
  const int tx2 = tid & 15;
  const int ty2 = tid >> 4;  // 0..15
#pragma unroll
  for (int r = ty2; r < 32; r += 16) {
    unsigned v = (unsigned)cvt(tile[2 * tx2][r]) |
                 ((unsigned)cvt(tile[2 * tx2 + 1][r]) << 16);
    *(unsigned*)&Wt[(bx + r) * EMB + by + 2 * tx2] = v;
  }
}

// ---------- fused QKV GEMM (BK=32, triple-buffer, counted vmcnt) ----------
// T4: never drain vmcnt to 0 in the loop. Per iter: wait vmcnt(4) (retire
// tile t's 4 per-wave loads; t+1's stay in flight) -> s_barrier -> issue
// tile t+2 -> compute t. 64B LDS rows with chunk-swizzle g(row)=(row>>1)&3
// (store-side pre-swizzled source + read-side XOR) -> 2-way reads = free.
__global__ __launch_bounds__(256) void k_gemm_qkv(
    const u16* __restrict__ xb, const u16* __restrict__ WqT,
    const u16* __restrict__ WkT, const u16* __restrict__ WvT,
    const float* __restrict__ bq, const float* __restrict__ bk,
    const float* __restrict__ bv, u16* __restrict__ Q, u16* __restrict__ K,
    u16* __restrict__ Vt) {
  __shared__ u16 Al[3][128 * 32];  // 8KB x3
  __shared__ u16 Bl[3][128 * 32];  // 8KB x3 (48 KB total -> 3 blocks/CU)
  const int tid = threadIdx.x;
  const int lane = tid & 63;
  const int w = tid >> 6;
  const int wr = w >> 1, wc = w & 1;
  const int lr = lane & 15, lg = lane >> 4;
  const int m0 = blockIdx.x * 128;
  const int nb = blockIdx.y;           // 0..23
  const int seg = nb >> 3;             // 0=Q 1=K 2=V
  const int n0 = (nb & 7) * 128;
  const u16* __restrict__ Bt = (seg == 0) ? WqT : (seg == 1) ? WkT : WvT;
  const float* __restrict__ bias = (seg == 0) ? bq : (seg == 1) ? bk : bv;

  f32x4 acc[4][4];
#pragma unroll
  for (int i = 0; i < 4; i++)
#pragma unroll
    for (int j = 0; j < 4; j++) acc[i][j] = (f32x4){0.f, 0.f, 0.f, 0.f};

  // staging: thread t -> row t>>2 (0..63, +64 for 2nd m-half), phys chunk
  // t&3. Pre-swizzled source chunk sc = (t&3) ^ g(row), g(row)=(row>>1)&3
  // (invariant under row+64). Linear LDS dest (rule 21).
  const int srow = tid >> 2;
  const int sc = (tid & 3) ^ ((tid >> 3) & 3);
  const u16* ga0 = xb + (m0 + srow) * EMB + sc * 8;
  const u16* gb0 = Bt + (n0 + srow) * EMB + sc * 8;
  const int lofs = w * 1024;  // wave-uniform LDS byte base

  // prologue: stage tiles 0 and 1
  gload16(ga0, (char*)Al[0] + lofs);
  gload16(ga0 + 64 * EMB, (char*)Al[0] + lofs + 4096);
  gload16(gb0, (char*)Bl[0] + lofs);
  gload16(gb0 + 64 * EMB, (char*)Bl[0] + lofs + 4096);
  gload16(ga0 + 32, (char*)Al[1] + lofs);
  gload16(ga0 + 64 * EMB + 32, (char*)Al[1] + lofs + 4096);
  gload16(gb0 + 32, (char*)Bl[1] + lofs);
  gload16(gb0 + 64 * EMB + 32, (char*)Bl[1] + lofs + 4096);

  // read-side swizzle: row = (16-mult) + lr -> g(row) = (lr>>1)&3
  const int pc = (lg ^ ((lr >> 1) & 3)) * 16;

  int cur = 0;
  for (int k0 = 0; k0 < EMB; k0 += 32) {
    // counted wait: retire tile t's 4 loads; tile t+1's stay in flight
    if (k0 + 32 < EMB)
      asm volatile("s_waitcnt vmcnt(4)" ::: "memory");
    else
      asm volatile("s_waitcnt vmcnt(0)" ::: "memory");
    __builtin_amdgcn_s_barrier();
    if (k0 + 64 < EMB) {  // issue tile t+2 into buf of finished tile t-1
      int b2 = cur + 2;
      if (b2 >= 3) b2 -= 3;
      const int kn = k0 + 64;
      gload16(ga0 + kn, (char*)Al[b2] + lofs);
      gload16(ga0 + 64 * EMB + kn, (char*)Al[b2] + lofs + 4096);
      gload16(gb0 + kn, (char*)Bl[b2] + lofs);
      gload16(gb0 + 64 * EMB + kn, (char*)Bl[b2] + lofs + 4096);
    }
    const char* Ac = (const char*)Al[cur];
    const char* Bc = (const char*)Bl[cur];
    u16x8 af[4], bfr[4];
#pragma unroll
    for (int mi = 0; mi < 4; mi++)
      af[mi] = *(const u16x8*)(Ac + (wr * 64 + mi * 16 + lr) * 64 + pc);
#pragma unroll
    for (int ni = 0; ni < 4; ni++)
      bfr[ni] = *(const u16x8*)(Bc + (wc * 64 + ni * 16 + lr) * 64 + pc);
#pragma unroll
    for (int mi = 0; mi < 4; mi++)
#pragma unroll
      for (int ni = 0; ni < 4; ni++)
        acc[mi][ni] = __builtin_amdgcn_mfma_f32_16x16x32_bf16(
            asbf(af[mi]), asbf(bfr[ni]), acc[mi][ni], 0, 0, 0);
    cur = (cur == 2) ? 0 : cur + 1;
  }

  const int b = m0 >> 11;  // batch (block never straddles)
  if (seg == 2) {  // Vt[(b*16+h)*64+d][t]: 4 consecutive t -> ushort4
#pragma unroll
    for (int ni = 0; ni < 4; ni++) {
      const int n = n0 + wc * 64 + ni * 16 + lr;
      const float bv_ = bias[n];
      const int h = n >> 6, d = n & 63;
      u16* vrow = Vt + (((b * NHEADS + h) * HD) + d) * TT;
#pragma unroll
      for (int mi = 0; mi < 4; mi++) {
        const int t0 = (m0 + wr * 64 + mi * 16 + lg * 4) & 2047;
        ushort4 pk;
        pk.x = cvt(acc[mi][ni][0] + bv_);
        pk.y = cvt(acc[mi][ni][1] + bv_);
        pk.z = cvt(acc[mi][ni][2] + bv_);
        pk.w = cvt(acc[mi][ni][3] + bv_);
        *(ushort4*)&vrow[t0] = pk;
      }
    }
  } else {  // Q/K [(b*16+h)*2048+t][d]: scalar stores (r10-proven)
    u16* __restrict__ dst = (seg == 0) ? Q : K;
    const float qs = (seg == 0) ? 0.18033688011f : 1.0f;  // (1/8)*log2(e)
#pragma unroll
    for (int mi = 0; mi < 4; mi++) {
      const int lmb = wr * 64 + mi * 16 + lg * 4;
#pragma unroll
      for (int ni = 0; ni < 4; ni++) {
        const int n = n0 + wc * 64 + ni * 16 + lr;
        const float bv_ = bias[n];
        const int h = n >> 6, d = n & 63;
#pragma unroll
        for (int r = 0; r < 4; r++) {
          const int t = (m0 + lmb + r) & 2047;
          float v = (acc[mi][ni][r] + bv_) * qs;
          dst[(((b * NHEADS + h) * TT) + t) * HD + d] = cvt(v);
        }
      }
    }
  }
}

// ---------- causal flash attention (r8 kernel, proven 44.5 us) ----------
__global__ __launch_bounds__(512) void k_attn(const u16* __restrict__ Q,
                                              const u16* __restrict__ Kg,
                                              const u16* __restrict__ Vt,
                                              u16* __restrict__ AO) {
  __shared__ u16 Kl[2][64 * 64];   // 8KB x2
  __shared__ u16 Vl[2][64 * 64];   // 8KB x2
  const int tid = threadIdx.x;
  const int lane = tid & 63;
  const int w = tid >> 6;          // 0..7
  const int lr = lane & 15, lg = lane >> 4;
  const int bh = blockIdx.x;       // 0..31
  const int pair = blockIdx.y;     // 0..15
  const int lo = pair, hi = 31 - pair;
  const int qblk = (w < 4) ? hi : lo;      // this wave's q-block
  const int myend = qblk;                  // last k-tile index for this wave
  const int q0 = qblk * 64 + (w & 3) * 16;
  const u16* __restrict__ Qh = Q + bh * TT * HD;
  const u16* __restrict__ Kh = Kg + bh * TT * HD;
  const u16* __restrict__ Vh = Vt + bh * HD * TT;

  const int srow = tid >> 3;  // 0..63
  const int sgz = ((tid >> 3) & 3) | (((tid >> 6) & 1) << 2);
  const int sc = (tid & 7) ^ sgz;

  u16x8 qf[2];
  qf[0] = *(const u16x8*)&Qh[(q0 + lr) * HD + lg * 8];
  qf[1] = *(const u16x8*)&Qh[(q0 + lr) * HD + 32 + lg * 8];

  f32x4 accO[4];
#pragma unroll
  for (int i = 0; i < 4; i++) accO[i] = (f32x4){0.f, 0.f, 0.f, 0.f};
  float mst = -__builtin_inff();  // per-lane: running max of row q0+lr
  float lsum = 0.f;               // per-lane partial denominator

  const int nkt = hi + 1;  // block-uniform loop count

  gload16(Kh + srow * HD + sc * 8, (char*)Kl[0] + w * 1024);
  gload16(Vh + srow * TT + sc * 8, (char*)Vl[0] + w * 1024);
  __syncthreads();  // drains vmcnt

  for (int kt = 0; kt < nkt; ++kt) {
    const int k0 = kt * 64;
    const int cur = kt & 1;
    if (kt + 1 < nkt) {  // issue next-tile loads BEFORE compute (2-phase)
      const int kn = k0 + 64;
      gload16(Kh + (kn + srow) * HD + sc * 8, (char*)Kl[cur ^ 1] + w * 1024);
      gload16(Vh + srow * TT + kn + sc * 8, (char*)Vl[cur ^ 1] + w * 1024);
    }
    if (kt <= myend) {  // wave-uniform: lo-waves idle past their diagonal
      const char* Kc = (const char*)Kl[cur];
      const char* Vc = (const char*)Vl[cur];

      f32x4 s[4];
#pragma unroll
      for (int n = 0; n < 4; n++) s[n] = (f32x4){0.f, 0.f, 0.f, 0.f};
      __builtin_amdgcn_s_setprio(1);
#pragma unroll
      for (int n = 0; n < 4; n++) {
        // permuted K-row: lane's 16 score cols == PV A-frag slots
        const int kr =
            (lr & 3) + ((n & 1) << 2) + ((lr >> 2) << 3) + ((n >> 1) << 5);
        const int gg = (kr & 3) | (((kr >> 3) & 1) << 2);
#pragma unroll
        for (int dh = 0; dh < 2; dh++) {
          const int bo = ((dh * 4 + lg) ^ gg) << 4;
          u16x8 kf = *(const u16x8*)(Kc + kr * 128 + bo);
          s[n] = __builtin_amdgcn_mfma_f32_16x16x32_bf16(asbf(kf), asbf(qf[dh]),
                                                         s[n], 0, 0, 0);
        }
      }
      __builtin_amdgcn_s_setprio(0);
      if (kt == myend) {  // diagonal tile: causal mask (col > my q-row)
        const int rowq = q0 + lr;
#pragma unroll
        for (int n = 0; n < 4; n++) {
          const int cb = k0 + ((n & 1) << 2) + (lg << 3) + ((n >> 1) << 5);
#pragma unroll
          for (int r = 0; r < 4; r++)
            if (cb + r > rowq) s[n][r] = -__builtin_inff();
        }
      }
      // lane-local row max over this tile's 16 cols
      float m01 = fmaxf(fmaxf(s[0][0], s[0][1]), fmaxf(s[0][2], s[0][3]));
      float m1 = fmaxf(fmaxf(s[1][0], s[1][1]), fmaxf(s[1][2], s[1][3]));
      float m2 = fmaxf(fmaxf(s[2][0], s[2][1]), fmaxf(s[2][2], s[2][3]));
      float m3 = fmaxf(fmaxf(s[3][0], s[3][1]), fmaxf(s[3][2], s[3][3]));
      float lmax = fmaxf(fmaxf(m01, m1), fmaxf(m2, m3));
      // defer-max (log2 domain, THR=11 bits). -inf tile0 forces rescale.
      if (!__all(lmax - mst <= 11.0f)) {
        float rm = lmax;
        rm = fmaxf(rm, __shfl_xor(rm, 16));
        rm = fmaxf(rm, __shfl_xor(rm, 32));
        float mnew = fmaxf(mst, rm);
        float corr = exp2f(mst - mnew);
        lsum *= corr;
        mst = mnew;
#pragma unroll
        for (int r = 0; r < 4; r++) {  // corr for accO's q-row (lg*4+r)
          float ca = __shfl(corr, 20 * lg + r);
#pragma unroll
          for (int dt = 0; dt < 4; dt++) accO[dt][r] *= ca;
        }
      }
      // P in-register: p[n][r] are exactly PV A-frag slots
      float p[4][4];
      float ls = 0.f;
#pragma unroll
      for (int n = 0; n < 4; n++)
#pragma unroll
        for (int r = 0; r < 4; r++) {
          p[n][r] = exp2f(s[n][r] - mst);
          ls += p[n][r];
        }
      lsum += ls;
      u16x8 a1, a2;
#pragma unroll
      for (int r = 0; r < 4; r++) {
        a1[r] = cvt(p[0][r]);
        a1[4 + r] = cvt(p[1][r]);
        a2[r] = cvt(p[2][r]);
        a2[4 + r] = cvt(p[3][r]);
      }
      __builtin_amdgcn_s_setprio(1);
#pragma unroll
      for (int dt = 0; dt < 4; dt++) {
        const int row = dt * 16 + lr;
        const int gg = (row & 3) | (((row >> 3) & 1) << 2);
        const int bo0 = ((lg ^ gg) << 4);
        const int bo1 = (((4 + lg) ^ gg) << 4);
        u16x8 vf0 = *(const u16x8*)(Vc + row * 128 + bo0);
        u16x8 vf1 = *(const u16x8*)(Vc + row * 128 + bo1);
        accO[dt] = __builtin_amdgcn_mfma_f32_16x16x32_bf16(asbf(a1), asbf(vf0),
                                                           accO[dt], 0, 0, 0);
        accO[dt] = __builtin_amdgcn_mfma_f32_16x16x32_bf16(asbf(a2), asbf(vf1),
                                                           accO[dt], 0, 0, 0);
      }
      __builtin_amdgcn_s_setprio(0);
    }
    __syncthreads();  // drains vmcnt: next buf staged; cur free to overwrite
  }
  // denominator: reduce the 4 lanes sharing this q-row, then redistribute
  float t = lsum;
  t += __shfl_xor(t, 16);
  t += __shfl_xor(t, 32);
  float rinv = 1.0f / t;
  float ra[4];
#pragma unroll
  for (int r = 0; r < 4; r++) ra[r] = __shfl(rinv, 20 * lg + r);
  const int b = bh >> 4, h = bh & 15;
#pragma unroll
  for (int dt = 0; dt < 4; dt++)
#pragma unroll
    for (int r = 0; r < 4; r++) {
      const int row = q0 + lg * 4 + r;
      const int d = h * 64 + dt * 16 + lr;
      AO[(b * TT + row) * EMB + d] = cvt(accO[dt][r] * ra[r]);
    }
}

// ---------- output projection GEMM (swapped frags, float4 epilogue) -------
__global__ __launch_bounds__(256) void k_gemm_out(const u16* __restrict__ AO,
                                                  const u16* __restrict__ WoT,
                                                  const float* __restrict__ bo,
                                                  float* __restrict__ out) {
  __shared__ u16 Al[128 * 64];
  __shared__ u16 Bl[128 * 64];
  const int tid = threadIdx.x;
  const int lane = tid & 63;
  const int w = tid >> 6;
  const int wr = w >> 1, wc = w & 1;
  const int lr = lane & 15, lg = lane >> 4;
  const int m0 = blockIdx.x * 128;
  const int n0 = blockIdx.y * 128;

  f32x4 acc[4][4];
#pragma unroll
  for (int i = 0; i < 4; i++)
#pragma unroll
    for (int j = 0; j < 4; j++) acc[i][j] = (f32x4){0.f, 0.f, 0.f, 0.f};

  const int srow = tid >> 3;
  const int sgz = ((tid >> 3) & 3) | (((tid >> 6) & 1) << 2);
  const int sc = (tid & 7) ^ sgz;
  const u16* ga0 = AO + (m0 + srow) * EMB + sc * 8;
  const u16* gb0 = WoT + (n0 + srow) * EMB + sc * 8;
  char* la0 = (char*)Al + w * 1024;
  char* lb0 = (char*)Bl + w * 1024;
  const int gfr = (lr & 3) | (((lr >> 3) & 1) << 2);

  for (int k0 = 0; k0 < EMB; k0 += 64) {
#pragma unroll
    for (int m = 0; m < 4; m++) {
      gload16(ga0 + (32 * m) * EMB + k0, la0 + m * 4096);
      gload16(gb0 + (32 * m) * EMB + k0, lb0 + m * 4096);
    }
    __syncthreads();
    u16x8 af[4][2], bfr[4][2];
#pragma unroll
    for (int hh = 0; hh < 2; hh++) {
      const int pc = ((hh * 4 + lg) ^ gfr) * 16;
#pragma unroll
      for (int mi = 0; mi < 4; mi++)
        af[mi][hh] =
            *(const u16x8*)((char*)Al + (wr * 64 + mi * 16 + lr) * 128 + pc);
#pragma unroll
      for (int ni = 0; ni < 4; ni++)
        bfr[ni][hh] =
            *(const u16x8*)((char*)Bl + (wc * 64 + ni * 16 + lr) * 128 + pc);
    }
    // swapped: C rows = n (lane holds 4 consecutive n at fixed m)
#pragma unroll
    for (int hh = 0; hh < 2; hh++)
#pragma unroll
      for (int mi = 0; mi < 4; mi++)
#pragma unroll
        for (int ni = 0; ni < 4; ni++)
          acc[mi][ni] = __builtin_amdgcn_mfma_f32_16x16x32_bf16(
              asbf(bfr[ni][hh]), asbf(af[mi][hh]), acc[mi][ni], 0, 0, 0);
    __syncthreads();
  }

#pragma unroll
  for (int ni = 0; ni < 4; ni++) {
    const int nbase = n0 + wc * 64 + ni * 16 + lg * 4;
    const float4 bv4 = *(const float4*)&bo[nbase];
#pragma unroll
    for (int mi = 0; mi < 4; mi++) {
      const int m = m0 + wr * 64 + mi * 16 + lr;
      float4 v;
      v.x = acc[mi][ni][0] + bv4.x;
      v.y = acc[mi][ni][1] + bv4.y;
      v.z = acc[mi][ni][2] + bv4.z;
      v.w = acc[mi][ni][3] + bv4.w;
      *(float4*)&out[m * EMB + nbase] = v;
    }
  }
}

// ---------- launch ----------
extern "C" void kernel_launch(void* const* d_in, const int* in_sizes, int n_in,
                              void* d_out, int out_size, void* d_ws,
                              size_t ws_size, hipStream_t stream) {
  const float* x = (const float*)d_in[0];
  const float* Wq = (const float*)d_in[1];
  const float* bq = (const float*)d_in[2];
  const float* Wk = (const float*)d_in[3];
  const float* bk = (const float*)d_in[4];
  const float* Wv = (const float*)d_in[5];
  const float* bv = (const float*)d_in[6];
  const float* Wo = (const float*)d_in[7];
  const float* bo = (const float*)d_in[8];
  float* out = (float*)d_out;

  char* ws = (char*)d_ws;
  u16* xb = (u16*)ws;                      // 8 MB (reused as AO)
  u16* WqT = (u16*)(ws + (8u << 20));      // 2 MB
  u16* WkT = (u16*)(ws + (10u << 20));     // 2 MB
  u16* WvT = (u16*)(ws + (12u << 20));     // 2 MB
  u16* WoT = (u16*)(ws + (14u << 20));     // 2 MB
  u16* Qb = (u16*)(ws + (16u << 20));      // 8 MB
  u16* Kb = (u16*)(ws + (24u << 20));      // 8 MB
  u16* Vtb = (u16*)(ws + (32u << 20));     // 8 MB (total 40 MB)
  u16* AO = xb;

  k_prep<<<6144, 256, 0, stream>>>(x, xb, Wq, Wk, Wv, Wo, WqT, WkT, WvT, WoT);
  k_gemm_qkv<<<dim3(32, 24), 256, 0, stream>>>(xb, WqT, WkT, WvT, bq, bk, bv,
                                               Qb, Kb, Vtb);
  k_attn<<<dim3(32, 16), 512, 0, stream>>>(Qb, Kb, Vtb, AO);
  k_gemm_out<<<dim3(32, 8), 256, 0, stream>>>(AO, WoT, bo, out);
}

// Round 14
// 117.093 us; speedup vs baseline: 1.1303x; 1.0181x over previous
//
#include <hip/hip_runtime.h>

typedef unsigned short u16;
typedef u16 u16x8 __attribute__((ext_vector_type(8)));
typedef __bf16 bf16x8 __attribute__((ext_vector_type(8)));
typedef float f32x4 __attribute__((ext_vector_type(4)));

#define EMB 1024
#define TT 2048
#define BB 2
#define NHEADS 16
#define HD 64
#define MTOT (BB * TT)  // 4096

// ---------- helpers ----------
__device__ __forceinline__ u16 cvt(float f) {  // native f32->bf16 (RTNE)
  return __builtin_bit_cast(u16, (__bf16)f);
}

__device__ __forceinline__ bf16x8 asbf(u16x8 v) {
  return __builtin_bit_cast(bf16x8, v);
}

__device__ __forceinline__ void gload16(const void* g, void* l) {
  __builtin_amdgcn_global_load_lds(
      (const __attribute__((address_space(1))) void*)g,
      (__attribute__((address_space(3))) void*)l, 16, 0, 0);
}

// ---------- fused prep: x->bf16 + 4x W transpose->bf16, one launch ----------
__global__ __launch_bounds__(256) void k_prep(
    const float* __restrict__ x, u16* __restrict__ xb,
    const float* __restrict__ W0, const float* __restrict__ W1,
    const float* __restrict__ W2, const float* __restrict__ W3,
    u16* __restrict__ T0, u16* __restrict__ T1, u16* __restrict__ T2,
    u16* __restrict__ T3) {
  __shared__ float tile[32][33];
  const int bid = blockIdx.x;
  const int tid = threadIdx.x;
  if (bid >= 4096) {  // x conversion: 2048 blocks x 2048 elems
    int i = (bid - 4096) * 256 + tid;
    float4 a = ((const float4*)x)[i * 2];
    float4 b = ((const float4*)x)[i * 2 + 1];
    u16x8 o;
    o[0] = cvt(a.x); o[1] = cvt(a.y); o[2] = cvt(a.z); o[3] = cvt(a.w);
    o[4] = cvt(b.x); o[5] = cvt(b.y); o[6] = cvt(b.z); o[7] = cvt(b.w);
    ((u16x8*)xb)[i] = o;
    return;
  }
  const int z = bid >> 10;  // which W
  const float* __restrict__ W = (z == 0) ? W0 : (z == 1) ? W1 : (z == 2) ? W2 : W3;
  u16* __restrict__ Wt = (z == 0) ? T0 : (z == 1) ? T1 : (z == 2) ? T2 : T3;
  const int b = bid & 1023;
  const int bx = (b & 31) * 32, by = (b >> 5) * 32;
  const int tx = tid & 31;
  const int ty = tid >> 5;  // 0..7
#pragma unroll
  for (int r = ty; r < 32; r += 8) tile[r][tx] = W[(by + r) * EMB + bx + tx];
  __syncthreads();
  // vectorized transposed store: each thread packs 2 cols into one dword
  const int tx2 = tid & 15;
  const int ty2 = tid >> 4;  // 0..15
#pragma unroll
  for (int r = ty2; r < 32; r += 16) {
    unsigned v = (unsigned)cvt(tile[2 * tx2][r]) |
                 ((unsigned)cvt(tile[2 * tx2 + 1][r]) << 16);
    *(unsigned*)&Wt[(bx + r) * EMB + by + 2 * tx2] = v;
  }
}

// ---------- fused QKV GEMM (wave-private, barrier-free pipeline) ----------
// Each wave owns a 64x64 output tile and PRIVATE LDS (A-half + B-half,
// double-buffered): stage k+1 -> s_waitcnt vmcnt(8) (retire k; k+1 in
// flight) -> ds_read k -> 16 MFMA. Zero barriers: vmcnt is per-wave, LDS
// regions private, in-order issue makes gload-write vs prior ds_read safe.
// 64B-row chunk swizzle g(row)=(row>>1)&3 both sides (r12: 0 conflicts).
__global__ __launch_bounds__(256) void k_gemm_qkv(
    const u16* __restrict__ xb, const u16* __restrict__ WqT,
    const u16* __restrict__ WkT, const u16* __restrict__ WvT,
    const float* __restrict__ bq, const float* __restrict__ bk,
    const float* __restrict__ bv, u16* __restrict__ Q, u16* __restrict__ K,
    u16* __restrict__ Vt) {
  __shared__ u16 WS[4][2][2][2048];  // [wave][dbuf][A|B][4KB] = 64 KB
  const int tid = threadIdx.x;
  const int lane = tid & 63;
  const int w = tid >> 6;
  const int wr = w >> 1, wc = w & 1;
  const int lr = lane & 15, lg = lane >> 4;
  const int m0 = blockIdx.x * 128;
  const int nb = blockIdx.y;           // 0..23
  const int seg = nb >> 3;             // 0=Q 1=K 2=V
  const int n0 = (nb & 7) * 128;
  const u16* __restrict__ Bt = (seg == 0) ? WqT : (seg == 1) ? WkT : WvT;
  const float* __restrict__ bias = (seg == 0) ? bq : (seg == 1) ? bk : bv;

  f32x4 acc[4][4];
#pragma unroll
  for (int i = 0; i < 4; i++)
#pragma unroll
    for (int j = 0; j < 4; j++) acc[i][j] = (f32x4){0.f, 0.f, 0.f, 0.f};

  // staging (per wave): rows j*16 + (lane>>2), phys 16B chunk lane&3;
  // pre-swizzled source chunk sc = (lane&3) ^ g(row), g(row)=(row>>1)&3
  // = (lane>>3)&3 (invariant under row+16j). Linear LDS dest (rule 21).
  const int srow = lane >> 2;                       // 0..15
  const int sc = (lane & 3) ^ ((lane >> 3) & 3);
  const u16* gA = xb + (m0 + wr * 64 + srow) * EMB + sc * 8;
  const u16* gB = Bt + (n0 + wc * 64 + srow) * EMB + sc * 8;
  char* wbase = (char*)WS + w * 16384;  // wave-private 16 KB
  // read-side swizzle: row = mi*16+lr -> g = (lr>>1)&3
  const int pc = (lg ^ ((lr >> 1) & 3)) * 16;

  // prologue: stage k-step 0 into buf 0 (A at +0, B at +4096)
#pragma unroll
  for (int j = 0; j < 4; j++) {
    gload16(gA + j * 16 * EMB, wbase + j * 1024);
    gload16(gB + j * 16 * EMB, wbase + 4096 + j * 1024);
  }

  for (int k0 = 0; k0 < EMB; k0 += 32) {
    const int cur = (k0 >> 5) & 1;
    char* bcur = wbase + cur * 8192;
    if (k0 + 32 < EMB) {  // stage k+1 into the other buffer, then retire k
      char* bnxt = wbase + (cur ^ 1) * 8192;
      const int kn = k0 + 32;
#pragma unroll
      for (int j = 0; j < 4; j++) {
        gload16(gA + j * 16 * EMB + kn, bnxt + j * 1024);
        gload16(gB + j * 16 * EMB + kn, bnxt + 4096 + j * 1024);
      }
      asm volatile("s_waitcnt vmcnt(8)" ::: "memory");
    } else {
      asm volatile("s_waitcnt vmcnt(0)" ::: "memory");
    }
    __builtin_amdgcn_sched_barrier(0);
    u16x8 af[4], bf[4];
#pragma unroll
    for (int mi = 0; mi < 4; mi++)
      af[mi] = *(const u16x8*)(bcur + (mi * 16 + lr) * 64 + pc);
#pragma unroll
    for (int ni = 0; ni < 4; ni++)
      bf[ni] = *(const u16x8*)(bcur + 4096 + (ni * 16 + lr) * 64 + pc);
    __builtin_amdgcn_s_setprio(1);
#pragma unroll
    for (int mi = 0; mi < 4; mi++)
#pragma unroll
      for (int ni = 0; ni < 4; ni++)
        acc[mi][ni] = __builtin_amdgcn_mfma_f32_16x16x32_bf16(
            asbf(af[mi]), asbf(bf[ni]), acc[mi][ni], 0, 0, 0);
    __builtin_amdgcn_s_setprio(0);
  }

  const int b = m0 >> 11;  // batch (block never straddles)
  if (seg == 2) {  // Vt[(b*16+h)*64+d][t]: 4 consecutive t -> ushort4
#pragma unroll
    for (int ni = 0; ni < 4; ni++) {
      const int n = n0 + wc * 64 + ni * 16 + lr;
      const float bv_ = bias[n];
      const int h = n >> 6, d = n & 63;
      u16* vrow = Vt + (((b * NHEADS + h) * HD) + d) * TT;
#pragma unroll
      for (int mi = 0; mi < 4; mi++) {
        const int t0 = (m0 + wr * 64 + mi * 16 + lg * 4) & 2047;
        ushort4 pk;
        pk.x = cvt(acc[mi][ni][0] + bv_);
        pk.y = cvt(acc[mi][ni][1] + bv_);
        pk.z = cvt(acc[mi][ni][2] + bv_);
        pk.w = cvt(acc[mi][ni][3] + bv_);
        *(ushort4*)&vrow[t0] = pk;
      }
    }
  } else {  // Q/K [(b*16+h)*2048+t][d]: scalar stores (r10-proven)
    u16* __restrict__ dst = (seg == 0) ? Q : K;
    const float qs = (seg == 0) ? 0.18033688011f : 1.0f;  // (1/8)*log2(e)
#pragma unroll
    for (int mi = 0; mi < 4; mi++) {
      const int lmb = wr * 64 + mi * 16 + lg * 4;
#pragma unroll
      for (int ni = 0; ni < 4; ni++) {
        const int n = n0 + wc * 64 + ni * 16 + lr;
        const float bv_ = bias[n];
        const int h = n >> 6, d = n & 63;
#pragma unroll
        for (int r = 0; r < 4; r++) {
          const int t = (m0 + lmb + r) & 2047;
          float v = (acc[mi][ni][r] + bv_) * qs;
          dst[(((b * NHEADS + h) * TT) + t) * HD + d] = cvt(v);
        }
      }
    }
  }
}

// ---------- causal flash attention (r8 kernel, proven 44.5 us) ----------
__global__ __launch_bounds__(512) void k_attn(const u16* __restrict__ Q,
                                              const u16* __restrict__ Kg,
                                              const u16* __restrict__ Vt,
                                              u16* __restrict__ AO) {
  __shared__ u16 Kl[2][64 * 64];   // 8KB x2
  __shared__ u16 Vl[2][64 * 64];   // 8KB x2
  const int tid = threadIdx.x;
  const int lane = tid & 63;
  const int w = tid >> 6;          // 0..7
  const int lr = lane & 15, lg = lane >> 4;
  const int bh = blockIdx.x;       // 0..31
  const int pair = blockIdx.y;     // 0..15
  const int lo = pair, hi = 31 - pair;
  const int qblk = (w < 4) ? hi : lo;      // this wave's q-block
  const int myend = qblk;                  // last k-tile index for this wave
  const int q0 = qblk * 64 + (w & 3) * 16;
  const u16* __restrict__ Qh = Q + bh * TT * HD;
  const u16* __restrict__ Kh = Kg + bh * TT * HD;
  const u16* __restrict__ Vh = Vt + bh * HD * TT;

  const int srow = tid >> 3;  // 0..63
  const int sgz = ((tid >> 3) & 3) | (((tid >> 6) & 1) << 2);
  const int sc = (tid & 7) ^ sgz;

  u16x8 qf[2];
  qf[0] = *(const u16x8*)&Qh[(q0 + lr) * HD + lg * 8];
  qf[1] = *(const u16x8*)&Qh[(q0 + lr) * HD + 32 + lg * 8];

  f32x4 accO[4];
#pragma unroll
  for (int i = 0; i < 4; i++) accO[i] = (f32x4){0.f, 0.f, 0.f, 0.f};
  float mst = -__builtin_inff();  // per-lane: running max of row q0+lr
  float lsum = 0.f;               // per-lane partial denominator

  const int nkt = hi + 1;  // block-uniform loop count

  gload16(Kh + srow * HD + sc * 8, (char*)Kl[0] + w * 1024);
  gload16(Vh + srow * TT + sc * 8, (char*)Vl[0] + w * 1024);
  __syncthreads();  // drains vmcnt

  for (int kt = 0; kt < nkt; ++kt) {
    const int k0 = kt * 64;
    const int cur = kt & 1;
    if (kt + 1 < nkt) {  // issue next-tile loads BEFORE compute (2-phase)
      const int kn = k0 + 64;
      gload16(Kh + (kn + srow) * HD + sc * 8, (char*)Kl[cur ^ 1] + w * 1024);
      gload16(Vh + srow * TT + kn + sc * 8, (char*)Vl[cur ^ 1] + w * 1024);
    }
    if (kt <= myend) {  // wave-uniform: lo-waves idle past their diagonal
      const char* Kc = (const char*)Kl[cur];
      const char* Vc = (const char*)Vl[cur];

      f32x4 s[4];
#pragma unroll
      for (int n = 0; n < 4; n++) s[n] = (f32x4){0.f, 0.f, 0.f, 0.f};
      __builtin_amdgcn_s_setprio(1);
#pragma unroll
      for (int n = 0; n < 4; n++) {
        // permuted K-row: lane's 16 score cols == PV A-frag slots
        const int kr =
            (lr & 3) + ((n & 1) << 2) + ((lr >> 2) << 3) + ((n >> 1) << 5);
        const int gg = (kr & 3) | (((kr >> 3) & 1) << 2);
#pragma unroll
        for (int dh = 0; dh < 2; dh++) {
          const int bo = ((dh * 4 + lg) ^ gg) << 4;
          u16x8 kf = *(const u16x8*)(Kc + kr * 128 + bo);
          s[n] = __builtin_amdgcn_mfma_f32_16x16x32_bf16(asbf(kf), asbf(qf[dh]),
                                                         s[n], 0, 0, 0);
        }
      }
      __builtin_amdgcn_s_setprio(0);
      if (kt == myend) {  // diagonal tile: causal mask (col > my q-row)
        const int rowq = q0 + lr;
#pragma unroll
        for (int n = 0; n < 4; n++) {
          const int cb = k0 + ((n & 1) << 2) + (lg << 3) + ((n >> 1) << 5);
#pragma unroll
          for (int r = 0; r < 4; r++)
            if (cb + r > rowq) s[n][r] = -__builtin_inff();
        }
      }
      // lane-local row max over this tile's 16 cols
      float m01 = fmaxf(fmaxf(s[0][0], s[0][1]), fmaxf(s[0][2], s[0][3]));
      float m1 = fmaxf(fmaxf(s[1][0], s[1][1]), fmaxf(s[1][2], s[1][3]));
      float m2 = fmaxf(fmaxf(s[2][0], s[2][1]), fmaxf(s[2][2], s[2][3]));
      float m3 = fmaxf(fmaxf(s[3][0], s[3][1]), fmaxf(s[3][2], s[3][3]));
      float lmax = fmaxf(fmaxf(m01, m1), fmaxf(m2, m3));
      // defer-max (log2 domain, THR=11 bits). -inf tile0 forces rescale.
      if (!__all(lmax - mst <= 11.0f)) {
        float rm = lmax;
        rm = fmaxf(rm, __shfl_xor(rm, 16));
        rm = fmaxf(rm, __shfl_xor(rm, 32));
        float mnew = fmaxf(mst, rm);
        float corr = exp2f(mst - mnew);
        lsum *= corr;
        mst = mnew;
#pragma unroll
        for (int r = 0; r < 4; r++) {  // corr for accO's q-row (lg*4+r)
          float ca = __shfl(corr, 20 * lg + r);
#pragma unroll
          for (int dt = 0; dt < 4; dt++) accO[dt][r] *= ca;
        }
      }
      // P in-register: p[n][r] are exactly PV A-frag slots
      float p[4][4];
      float ls = 0.f;
#pragma unroll
      for (int n = 0; n < 4; n++)
#pragma unroll
        for (int r = 0; r < 4; r++) {
          p[n][r] = exp2f(s[n][r] - mst);
          ls += p[n][r];
        }
      lsum += ls;
      u16x8 a1, a2;
#pragma unroll
      for (int r = 0; r < 4; r++) {
        a1[r] = cvt(p[0][r]);
        a1[4 + r] = cvt(p[1][r]);
        a2[r] = cvt(p[2][r]);
        a2[4 + r] = cvt(p[3][r]);
      }
      __builtin_amdgcn_s_setprio(1);
#pragma unroll
      for (int dt = 0; dt < 4; dt++) {
        const int row = dt * 16 + lr;
        const int gg = (row & 3) | (((row >> 3) & 1) << 2);
        const int bo0 = ((lg ^ gg) << 4);
        const int bo1 = (((4 + lg) ^ gg) << 4);
        u16x8 vf0 = *(const u16x8*)(Vc + row * 128 + bo0);
        u16x8 vf1 = *(const u16x8*)(Vc + row * 128 + bo1);
        accO[dt] = __builtin_amdgcn_mfma_f32_16x16x32_bf16(asbf(a1), asbf(vf0),
                                                           accO[dt], 0, 0, 0);
        accO[dt] = __builtin_amdgcn_mfma_f32_16x16x32_bf16(asbf(a2), asbf(vf1),
                                                           accO[dt], 0, 0, 0);
      }
      __builtin_amdgcn_s_setprio(0);
    }
    __syncthreads();  // drains vmcnt: next buf staged; cur free to overwrite
  }
  // denominator: reduce the 4 lanes sharing this q-row, then redistribute
  float t = lsum;
  t += __shfl_xor(t, 16);
  t += __shfl_xor(t, 32);
  float rinv = 1.0f / t;
  float ra[4];
#pragma unroll
  for (int r = 0; r < 4; r++) ra[r] = __shfl(rinv, 20 * lg + r);
  const int b = bh >> 4, h = bh & 15;
#pragma unroll
  for (int dt = 0; dt < 4; dt++)
#pragma unroll
    for (int r = 0; r < 4; r++) {
      const int row = q0 + lg * 4 + r;
      const int d = h * 64 + dt * 16 + lr;
      AO[(b * TT + row) * EMB + d] = cvt(accO[dt][r] * ra[r]);
    }
}

// ---------- output projection GEMM (swapped frags, float4 epilogue) -------
__global__ __launch_bounds__(256) void k_gemm_out(const u16* __restrict__ AO,
                                                  const u16* __restrict__ WoT,
                                                  const float* __restrict__ bo,
                                                  float* __restrict__ out) {
  __shared__ u16 Al[128 * 64];
  __shared__ u16 Bl[128 * 64];
  const int tid = threadIdx.x;
  const int lane = tid & 63;
  const int w = tid >> 6;
  const int wr = w >> 1, wc = w & 1;
  const int lr = lane & 15, lg = lane >> 4;
  const int m0 = blockIdx.x * 128;
  const int n0 = blockIdx.y * 128;

  f32x4 acc[4][4];
#pragma unroll
  for (int i = 0; i < 4; i++)
#pragma unroll
    for (int j = 0; j < 4; j++) acc[i][j] = (f32x4){0.f, 0.f, 0.f, 0.f};

  const int srow = tid >> 3;
  const int sgz = ((tid >> 3) & 3) | (((tid >> 6) & 1) << 2);
  const int sc = (tid & 7) ^ sgz;
  const u16* ga0 = AO + (m0 + srow) * EMB + sc * 8;
  const u16* gb0 = WoT + (n0 + srow) * EMB + sc * 8;
  char* la0 = (char*)Al + w * 1024;
  char* lb0 = (char*)Bl + w * 1024;
  const int gfr = (lr & 3) | (((lr >> 3) & 1) << 2);

  for (int k0 = 0; k0 < EMB; k0 += 64) {
#pragma unroll
    for (int m = 0; m < 4; m++) {
      gload16(ga0 + (32 * m) * EMB + k0, la0 + m * 4096);
      gload16(gb0 + (32 * m) * EMB + k0, lb0 + m * 4096);
    }
    __syncthreads();
    u16x8 af[4][2], bfr[4][2];
#pragma unroll
    for (int hh = 0; hh < 2; hh++) {
      const int pc = ((hh * 4 + lg) ^ gfr) * 16;
#pragma unroll
      for (int mi = 0; mi < 4; mi++)
        af[mi][hh] =
            *(const u16x8*)((char*)Al + (wr * 64 + mi * 16 + lr) * 128 + pc);
#pragma unroll
      for (int ni = 0; ni < 4; ni++)
        bfr[ni][hh] =
            *(const u16x8*)((char*)Bl + (wc * 64 + ni * 16 + lr) * 128 + pc);
    }
    // swapped: C rows = n (lane holds 4 consecutive n at fixed m)
#pragma unroll
    for (int hh = 0; hh < 2; hh++)
#pragma unroll
      for (int mi = 0; mi < 4; mi++)
#pragma unroll
        for (int ni = 0; ni < 4; ni++)
          acc[mi][ni] = __builtin_amdgcn_mfma_f32_16x16x32_bf16(
              asbf(bfr[ni][hh]), asbf(af[mi][hh]), acc[mi][ni], 0, 0, 0);
    __syncthreads();
  }

#pragma unroll
  for (int ni = 0; ni < 4; ni++) {
    const int nbase = n0 + wc * 64 + ni * 16 + lg * 4;
    const float4 bv4 = *(const float4*)&bo[nbase];
#pragma unroll
    for (int mi = 0; mi < 4; mi++) {
      const int m = m0 + wr * 64 + mi * 16 + lr;
      float4 v;
      v.x = acc[mi][ni][0] + bv4.x;
      v.y = acc[mi][ni][1] + bv4.y;
      v.z = acc[mi][ni][2] + bv4.z;
      v.w = acc[mi][ni][3] + bv4.w;
      *(float4*)&out[m * EMB + nbase] = v;
    }
  }
}

// ---------- launch ----------
extern "C" void kernel_launch(void* const* d_in, const int* in_sizes, int n_in,
                              void* d_out, int out_size, void* d_ws,
                              size_t ws_size, hipStream_t stream) {
  const float* x = (const float*)d_in[0];
  const float* Wq = (const float*)d_in[1];
  const float* bq = (const float*)d_in[2];
  const float* Wk = (const float*)d_in[3];
  const float* bk = (const float*)d_in[4];
  const float* Wv = (const float*)d_in[5];
  const float* bv = (const float*)d_in[6];
  const float* Wo = (const float*)d_in[7];
  const float* bo = (const float*)d_in[8];
  float* out = (float*)d_out;

  char* ws = (char*)d_ws;
  u16* xb = (u16*)ws;                      // 8 MB (reused as AO)
  u16* WqT = (u16*)(ws + (8u << 20));      // 2 MB
  u16* WkT = (u16*)(ws + (10u << 20));     // 2 MB
  u16* WvT = (u16*)(ws + (12u << 20));     // 2 MB
  u16* WoT = (u16*)(ws + (14u << 20));     // 2 MB
  u16* Qb = (u16*)(ws + (16u << 20));      // 8 MB
  u16* Kb = (u16*)(ws + (24u << 20));      // 8 MB
  u16* Vtb = (u16*)(ws + (32u << 20));     // 8 MB (total 40 MB)
  u16* AO = xb;

  k_prep<<<6144, 256, 0, stream>>>(x, xb, Wq, Wk, Wv, Wo, WqT, WkT, WvT, WoT);
  k_gemm_qkv<<<dim3(32, 24), 256, 0, stream>>>(xb, WqT, WkT, WvT, bq, bk, bv,
                                               Qb, Kb, Vtb);
  k_attn<<<dim3(32, 16), 512, 0, stream>>>(Qb, Kb, Vtb, AO);
  k_gemm_out<<<dim3(32, 8), 256, 0, stream>>>(AO, WoT, bo, out);
}